// Round 10
// baseline (251.288 us; speedup 1.0000x reference)
//
#include <hip/hip_runtime.h>
#include <hip/hip_bf16.h>
#include <math.h>

#define IN_CH 128
#define H_CH  64
#define PBLK  256      // partition blocks (pass A/C grid)
#define PTHR  512      // threads for pass A/C
#define BKT   256      // nodes per bucket
#define MAXBK 400      // max buckets (N <= 102400)

// ---------------- helpers ----------------

__device__ inline float bflo(unsigned u) { return __uint_as_float(u << 16); }
__device__ inline float bfhi(unsigned u) { return __uint_as_float(u & 0xffff0000u); }
__device__ inline unsigned short f2bf(float f) {   // round-to-nearest-even
    unsigned x = __float_as_uint(f);
    return (unsigned short)((x + 0x7fffu + ((x >> 16) & 1u)) >> 16);
}

// ---------------- CSR build: bucket partition, LDS atomics only ----------------

__global__ __launch_bounds__(PTHR) void passA(const int* __restrict__ ei, int E, int n,
                                              int nbk, int* __restrict__ blkhist) {
    __shared__ int hist[MAXBK];
    int tot = E + n;
    int CH = (tot + gridDim.x - 1) / gridDim.x;
    int beg = blockIdx.x * CH, end = min(tot, beg + CH);
    for (int k = threadIdx.x; k < nbk; k += blockDim.x) hist[k] = 0;
    __syncthreads();
    for (int idx = beg + threadIdx.x; idx < end; idx += blockDim.x) {
        int d = (idx < E) ? ei[E + idx] : (idx - E);
        atomicAdd(&hist[d >> 8], 1);
    }
    __syncthreads();
    for (int k = threadIdx.x; k < nbk; k += blockDim.x)
        blkhist[(size_t)blockIdx.x * nbk + k] = hist[k];
}

__global__ __launch_bounds__(PBLK) void passB1(const int* __restrict__ blkhist,
                                               int* __restrict__ blkbase,
                                               int* __restrict__ btot, int nbk) {
    __shared__ int sh[PBLK];
    int k = blockIdx.x, t = threadIdx.x;
    int v = blkhist[(size_t)t * nbk + k];
    sh[t] = v;
    __syncthreads();
    for (int off = 1; off < PBLK; off <<= 1) {
        int x = (t >= off) ? sh[t - off] : 0;
        __syncthreads();
        sh[t] += x;
        __syncthreads();
    }
    blkbase[(size_t)t * nbk + k] = sh[t] - v;
    if (t == PBLK - 1) btot[k] = sh[PBLK - 1];
}

__global__ __launch_bounds__(512) void passB2(const int* __restrict__ btot,
                                              int* __restrict__ bbase, int nbk, int tot) {
    __shared__ int sh[512];
    int t = threadIdx.x;
    int v = (t < nbk) ? btot[t] : 0;
    sh[t] = v;
    __syncthreads();
    for (int off = 1; off < 512; off <<= 1) {
        int x = (t >= off) ? sh[t - off] : 0;
        __syncthreads();
        sh[t] += x;
        __syncthreads();
    }
    if (t < nbk) bbase[t] = sh[t] - v;
    if (t == 0) bbase[nbk] = tot;
}

__global__ __launch_bounds__(PTHR) void passC(const int* __restrict__ ei, int E, int n, int nbk,
                                              const int* __restrict__ bbase,
                                              const int* __restrict__ blkbase,
                                              int2* __restrict__ pairs) {
    __shared__ int cur[MAXBK];
    int tot = E + n;
    int CH = (tot + gridDim.x - 1) / gridDim.x;
    int beg = blockIdx.x * CH, end = min(tot, beg + CH);
    for (int k = threadIdx.x; k < nbk; k += blockDim.x)
        cur[k] = bbase[k] + blkbase[(size_t)blockIdx.x * nbk + k];
    __syncthreads();
    for (int idx = beg + threadIdx.x; idx < end; idx += blockDim.x) {
        int s, d;
        if (idx < E) { s = ei[idx]; d = ei[E + idx]; }
        else         { s = idx - E; d = idx - E; }
        int pos = atomicAdd(&cur[d >> 8], 1);
        pairs[pos] = make_int2(s, d);
    }
}

__global__ __launch_bounds__(BKT) void passD(const int2* __restrict__ pairs,
                                             const int* __restrict__ bbase, int n, int nbk, int EP,
                                             int* __restrict__ esrc, int* __restrict__ offsets,
                                             float* __restrict__ dinv) {
    __shared__ int cnt[BKT];
    __shared__ int sh[BKT];
    __shared__ int cur[BKT];
    int k = blockIdx.x;
    int nbeg = k << 8;
    int t = threadIdx.x;
    int ebeg = bbase[k], eend = bbase[k + 1];
    cnt[t] = 0;
    __syncthreads();
    for (int e = ebeg + t; e < eend; e += BKT) {
        int2 p = pairs[e];
        atomicAdd(&cnt[p.y - nbeg], 1);
    }
    __syncthreads();
    int v = cnt[t];
    sh[t] = v;
    __syncthreads();
    for (int off = 1; off < BKT; off <<= 1) {
        int x = (t >= off) ? sh[t - off] : 0;
        __syncthreads();
        sh[t] += x;
        __syncthreads();
    }
    int lp = sh[t] - v;
    cur[t] = lp;
    int gn = nbeg + t;
    if (gn < n) {
        offsets[gn] = ebeg + lp;
        dinv[gn] = rsqrtf((float)v);
    }
    __syncthreads();
    for (int e = ebeg + t; e < eend; e += BKT) {
        int2 p = pairs[e];
        int pos = ebeg + atomicAdd(&cur[p.y - nbeg], 1);
        esrc[pos] = p.x;
    }
    if (k == 0 && t == 0) offsets[n] = EP;
}

// ---------------- GEMM: 128x64 tile, 512 threads (8 waves), 4x4 micro-tile ----------------
// W in LDS [K][68] (68-float row stride is the PROVEN conflict-free pad: r8 had 0
// conflicts with 68; r9's 66 gave 3.6M conflict cycles). X read directly from
// global (16-lane broadcast float4). 512-thread block amortizes the 33KB W tile
// over 8 waves -> 3 blocks/CU = 24 waves/CU (r9: 256-thread block = ~9 waves/CU,
// VALUBusy 30%, GEMM time K-independent => issue/latency bound on occupancy).
// FMA accumulation order identical to r8/r9 (bitwise-same output).
// GAT epilogue keeps e_ij fp32 (bf16 alphas FAILED r4). BIASF: add bias[col].

template <int K, bool GAT, bool OUTBF, bool BIASF>
__global__ __launch_bounds__(512, 6) void gemm_tiled(const float* __restrict__ X,
                                                     const float* __restrict__ W,
                                                     void* __restrict__ outv,
                                                     const float* __restrict__ asw,
                                                     const float* __restrict__ adw,
                                                     float* __restrict__ alpha_s,
                                                     float* __restrict__ alpha_d,
                                                     const float* __restrict__ bias, int n) {
    __shared__ float Wl[K][68];       // [k][col<=63], +4 pad (16B-aligned rows)
    int t  = threadIdx.x;
    int tx = t & 15, ty = t >> 4;     // ty in 0..31 -> 128 rows
    int r0 = blockIdx.x * 128;

    // stage W: K*64 floats by 512 threads, coalesced float4
#pragma unroll
    for (int i = 0; i < K / 32; i++) {
        int f = t + 512 * i;
        int k = f >> 4, cq = (f & 15) << 2;
        float4 v = *(const float4*)(W + k * H_CH + cq);
        *(float4*)&Wl[k][cq] = v;
    }
    __syncthreads();

    // per-thread X row pointers (rows >= n clamped to row 0; results discarded)
    const float* xp[4];
#pragma unroll
    for (int j = 0; j < 4; j++) {
        int r = r0 + 4 * ty + j;
        xp[j] = X + (size_t)(r < n ? r : 0) * K;
    }

    float acc[4][4] = {};
#pragma unroll 4
    for (int k4 = 0; k4 < K; k4 += 4) {
        float4 xr[4], wr[4];
#pragma unroll
        for (int j = 0; j < 4; j++)  xr[j]  = *(const float4*)(xp[j] + k4);
#pragma unroll
        for (int kk = 0; kk < 4; kk++) wr[kk] = *(const float4*)&Wl[k4 + kk][4 * tx];
#pragma unroll
        for (int j = 0; j < 4; j++) {
            acc[j][0] += xr[j].x * wr[0].x; acc[j][1] += xr[j].x * wr[0].y;
            acc[j][2] += xr[j].x * wr[0].z; acc[j][3] += xr[j].x * wr[0].w;
            acc[j][0] += xr[j].y * wr[1].x; acc[j][1] += xr[j].y * wr[1].y;
            acc[j][2] += xr[j].y * wr[1].z; acc[j][3] += xr[j].y * wr[1].w;
            acc[j][0] += xr[j].z * wr[2].x; acc[j][1] += xr[j].z * wr[2].y;
            acc[j][2] += xr[j].z * wr[2].z; acc[j][3] += xr[j].z * wr[2].w;
            acc[j][0] += xr[j].w * wr[3].x; acc[j][1] += xr[j].w * wr[3].y;
            acc[j][2] += xr[j].w * wr[3].z; acc[j][3] += xr[j].w * wr[3].w;
        }
    }

    float4 bvv = make_float4(0.f, 0.f, 0.f, 0.f);
    if (BIASF) bvv = *(const float4*)(bias + 4 * tx);

#pragma unroll
    for (int j = 0; j < 4; j++) {
        int r = r0 + 4 * ty + j;
        if (r < n) {
            float o0 = acc[j][0] + bvv.x, o1 = acc[j][1] + bvv.y;
            float o2 = acc[j][2] + bvv.z, o3 = acc[j][3] + bvv.w;
            if (OUTBF) {
                ushort4 o;
                o.x = f2bf(o0); o.y = f2bf(o1); o.z = f2bf(o2); o.w = f2bf(o3);
                *(ushort4*)((unsigned short*)outv + (size_t)r * H_CH + 4 * tx) = o;
            } else {
                *(float4*)((float*)outv + (size_t)r * H_CH + 4 * tx) =
                    make_float4(o0, o1, o2, o3);
            }
        }
    }

    if (GAT) {
        float va0 = asw[4 * tx], va1 = asw[4 * tx + 1], va2 = asw[4 * tx + 2], va3 = asw[4 * tx + 3];
        float vd0 = adw[4 * tx], vd1 = adw[4 * tx + 1], vd2 = adw[4 * tx + 2], vd3 = adw[4 * tx + 3];
#pragma unroll
        for (int j = 0; j < 4; j++) {
            float s1 = acc[j][0] * va0 + acc[j][1] * va1 + acc[j][2] * va2 + acc[j][3] * va3;
            float s2 = acc[j][0] * vd0 + acc[j][1] * vd1 + acc[j][2] * vd2 + acc[j][3] * vd3;
#pragma unroll
            for (int off = 8; off; off >>= 1) {
                s1 += __shfl_xor(s1, off, 16);
                s2 += __shfl_xor(s2, off, 16);
            }
            int r = r0 + 4 * ty + j;
            if (tx == 0 && r < n) { alpha_s[r] = s1; alpha_d[r] = s2; }
        }
    }
}

// ---------------- GAT gather: quarter-wave edges, single-pass unnormalized softmax --------

__global__ __launch_bounds__(256) void gat_gather(const unsigned short* __restrict__ h,
                                                  const int* __restrict__ offs,
                                                  const int* __restrict__ esrc,
                                                  const float* __restrict__ as,
                                                  const float* __restrict__ ad,
                                                  const float* __restrict__ bias,
                                                  float* __restrict__ out, int n) {
    __shared__ int2 sh[4][64];
    int lane = threadIdx.x & 63;
    int wid  = threadIdx.x >> 6;
    int q = lane >> 4, c = lane & 15;
    int gw = (blockIdx.x * blockDim.x + threadIdx.x) >> 6;
    int nw = (gridDim.x * blockDim.x) >> 6;
    float4 bv = *(const float4*)(bias + 4 * c);
    for (int i = gw; i < n; i += nw) {
        int beg = offs[i], end = offs[i + 1];
        float adi = ad[i];
        float a0 = 0.f, a1 = 0.f, a2 = 0.f, a3 = 0.f, s = 0.f;
        for (int base = beg; base < end; base += 64) {
            int l = base + lane;
            int sj = 0; float p = 0.f;
            if (l < end) {
                sj = esrc[l];
                float a = as[sj] + adi;
                float ev = a > 0.f ? a : 0.2f * a;   // leaky_relu 0.2
                p = __expf(ev);
            }
            sh[wid][lane] = make_int2(sj, __float_as_int(p));
            int cnt = min(64, end - base);
            int k = 0;
            for (; k + 8 <= cnt; k += 8) {
                int2 tA = sh[wid][k + q];
                int2 tB = sh[wid][k + 4 + q];
                float pA = __int_as_float(tA.y);
                float pB = __int_as_float(tB.y);
                uint2 uA = *(const uint2*)(h + (size_t)tA.x * H_CH + 4 * c);
                uint2 uB = *(const uint2*)(h + (size_t)tB.x * H_CH + 4 * c);
                a0 += pA * bflo(uA.x); a1 += pA * bfhi(uA.x);
                a2 += pA * bflo(uA.y); a3 += pA * bfhi(uA.y);
                a0 += pB * bflo(uB.x); a1 += pB * bfhi(uB.x);
                a2 += pB * bflo(uB.y); a3 += pB * bfhi(uB.y);
                s += pA + pB;
            }
            for (; k < cnt; k += 4) {
                int2 tA = sh[wid][k + q];          // zero-padded entries safe
                float pA = __int_as_float(tA.y);
                uint2 uA = *(const uint2*)(h + (size_t)tA.x * H_CH + 4 * c);
                a0 += pA * bflo(uA.x); a1 += pA * bfhi(uA.x);
                a2 += pA * bflo(uA.y); a3 += pA * bfhi(uA.y);
                s += pA;
            }
        }
        a0 += __shfl_xor(a0, 16, 64); a0 += __shfl_xor(a0, 32, 64);
        a1 += __shfl_xor(a1, 16, 64); a1 += __shfl_xor(a1, 32, 64);
        a2 += __shfl_xor(a2, 16, 64); a2 += __shfl_xor(a2, 32, 64);
        a3 += __shfl_xor(a3, 16, 64); a3 += __shfl_xor(a3, 32, 64);
        s  += __shfl_xor(s, 16, 64);  s  += __shfl_xor(s, 32, 64);
        float invs = 1.f / (s + 1e-16f);
        if (q == 0) {
            float4 o;
            o.x = fmaxf(a0 * invs + bv.x, 0.f);   // relu
            o.y = fmaxf(a1 * invs + bv.y, 0.f);
            o.z = fmaxf(a2 * invs + bv.z, 0.f);
            o.w = fmaxf(a3 * invs + bv.w, 0.f);
            *(float4*)(out + (size_t)i * H_CH + 4 * c) = o;
        }
    }
}

// ---------------- GCN gather: quarter-wave edges, bf16 input ----------------

template <bool OUTBF, bool RELU, bool BIASF>
__global__ __launch_bounds__(256) void gcn_gather(const unsigned short* __restrict__ h,
                                                  const int* __restrict__ offs,
                                                  const int* __restrict__ esrc,
                                                  const float* __restrict__ dinv,
                                                  const float* __restrict__ bias,
                                                  void* __restrict__ outv, int n) {
    __shared__ int2 sh[4][64];
    int lane = threadIdx.x & 63;
    int wid  = threadIdx.x >> 6;
    int q = lane >> 4, c = lane & 15;
    int gw = (blockIdx.x * blockDim.x + threadIdx.x) >> 6;
    int nw = (gridDim.x * blockDim.x) >> 6;
    float4 bv = make_float4(0.f, 0.f, 0.f, 0.f);
    if (BIASF) bv = *(const float4*)(bias + 4 * c);
    for (int i = gw; i < n; i += nw) {
        int beg = offs[i], end = offs[i + 1];
        float a0 = 0.f, a1 = 0.f, a2 = 0.f, a3 = 0.f;
        for (int base = beg; base < end; base += 64) {
            int l = base + lane;
            int sj = 0; float wl = 0.f;
            if (l < end) { sj = esrc[l]; wl = dinv[sj]; }
            sh[wid][lane] = make_int2(sj, __float_as_int(wl));
            int cnt = min(64, end - base);
            int k = 0;
            for (; k + 8 <= cnt; k += 8) {
                int2 tA = sh[wid][k + q];
                int2 tB = sh[wid][k + 4 + q];
                float pA = __int_as_float(tA.y);
                float pB = __int_as_float(tB.y);
                uint2 uA = *(const uint2*)(h + (size_t)tA.x * H_CH + 4 * c);
                uint2 uB = *(const uint2*)(h + (size_t)tB.x * H_CH + 4 * c);
                a0 += pA * bflo(uA.x); a1 += pA * bfhi(uA.x);
                a2 += pA * bflo(uA.y); a3 += pA * bfhi(uA.y);
                a0 += pB * bflo(uB.x); a1 += pB * bfhi(uB.x);
                a2 += pB * bflo(uB.y); a3 += pB * bfhi(uB.y);
            }
            for (; k < cnt; k += 4) {
                int2 tA = sh[wid][k + q];
                float pA = __int_as_float(tA.y);
                uint2 uA = *(const uint2*)(h + (size_t)tA.x * H_CH + 4 * c);
                a0 += pA * bflo(uA.x); a1 += pA * bfhi(uA.x);
                a2 += pA * bflo(uA.y); a3 += pA * bfhi(uA.y);
            }
        }
        a0 += __shfl_xor(a0, 16, 64); a0 += __shfl_xor(a0, 32, 64);
        a1 += __shfl_xor(a1, 16, 64); a1 += __shfl_xor(a1, 32, 64);
        a2 += __shfl_xor(a2, 16, 64); a2 += __shfl_xor(a2, 32, 64);
        a3 += __shfl_xor(a3, 16, 64); a3 += __shfl_xor(a3, 32, 64);
        float di = dinv[i];
        if (q == 0) {
            float v0 = a0 * di + bv.x, v1 = a1 * di + bv.y;
            float v2 = a2 * di + bv.z, v3 = a3 * di + bv.w;
            if (RELU) {
                v0 = fmaxf(v0, 0.f); v1 = fmaxf(v1, 0.f);
                v2 = fmaxf(v2, 0.f); v3 = fmaxf(v3, 0.f);
            }
            if (OUTBF) {
                ushort4 o;
                o.x = f2bf(v0); o.y = f2bf(v1); o.z = f2bf(v2); o.w = f2bf(v3);
                *(ushort4*)((unsigned short*)outv + (size_t)i * H_CH + 4 * c) = o;
            } else {
                *(float4*)((float*)outv + (size_t)i * H_CH + 4 * c) =
                    make_float4(v0, v1, v2, v3);
            }
        }
    }
}

// ---------------- launch ----------------

extern "C" void kernel_launch(void* const* d_in, const int* in_sizes, int n_in,
                              void* d_out, int out_size, void* d_ws, size_t ws_size,
                              hipStream_t stream) {
    const float* x       = (const float*)d_in[0];
    const int*   ei      = (const int*)d_in[1];
    const float* W_gat   = (const float*)d_in[2];
    const float* att_src = (const float*)d_in[3];
    const float* att_dst = (const float*)d_in[4];
    const float* b_gat   = (const float*)d_in[5];
    const float* W1      = (const float*)d_in[6];
    const float* b1      = (const float*)d_in[7];
    const float* W2      = (const float*)d_in[8];
    const float* b2      = (const float*)d_in[9];
    float* out = (float*)d_out;

    const int N  = in_sizes[0] / IN_CH;
    const int E  = in_sizes[1] / 2;
    const int EP = E + N;
    const int NBK = (N + BKT - 1) / BKT;
    const int NT  = (N + 127) / 128;   // gemm tiles (128 rows/block now)

    char* p = (char*)d_ws;
    auto alloc = [&](size_t bytes) -> void* {
        void* r = (void*)p;
        p += (bytes + 255) & ~(size_t)255;
        return r;
    };
    float* bufA    = (float*)alloc((size_t)N * H_CH * 4);   // fp32 scratch (gat out / agg3)
    unsigned short* hbf  = (unsigned short*)alloc((size_t)N * H_CH * 2);  // bf16 h (layer 1/2 gemm out)
    unsigned short* hbf2 = (unsigned short*)alloc((size_t)N * H_CH * 2);  // bf16 h2 (layer 2 gather out)
    float* alpha_s = (float*)alloc((size_t)N * 4);
    float* alpha_d = (float*)alloc((size_t)N * 4);
    float* dinv    = (float*)alloc((size_t)N * 4);
    int*   offsets = (int*)alloc((size_t)(N + 1) * 4);
    int*   esrc    = (int*)alloc((size_t)EP * 4);
    int2*  pairs   = (int2*)alloc((size_t)EP * 8);
    int*   blkhist = (int*)alloc((size_t)PBLK * NBK * 4);
    int*   blkbase = (int*)alloc((size_t)PBLK * NBK * 4);
    int*   btot    = (int*)alloc((size_t)(NBK + 1) * 4);
    int*   bbase   = (int*)alloc((size_t)(NBK + 1) * 4);

    // CSR build (no global atomics, no memsets)
    passA<<<PBLK, PTHR, 0, stream>>>(ei, E, N, NBK, blkhist);
    passB1<<<NBK, PBLK, 0, stream>>>(blkhist, blkbase, btot, NBK);
    passB2<<<1, 512, 0, stream>>>(btot, bbase, NBK, EP);
    passC<<<PBLK, PTHR, 0, stream>>>(ei, E, N, NBK, bbase, blkbase, pairs);
    passD<<<NBK, BKT, 0, stream>>>(pairs, bbase, N, NBK, EP, esrc, offsets, dinv);

    // layer 1: GAT. h1W bf16, alphas fp32 from GEMM accumulators; gather -> bufA (fp32)
    gemm_tiled<IN_CH, true, true, false><<<NT, 512, 0, stream>>>(x, W_gat, hbf, att_src, att_dst,
                                                                 alpha_s, alpha_d, nullptr, N);
    gat_gather<<<2048, 256, 0, stream>>>(hbf, offsets, esrc, alpha_s, alpha_d, b_gat, bufA, N);

    // layer 2: GCN + relu. gemm -> bf16 hbf; gather -> bf16 h2 (hbf2)
    gemm_tiled<H_CH, false, true, false><<<NT, 512, 0, stream>>>(bufA, W1, hbf, nullptr, nullptr,
                                                                 nullptr, nullptr, nullptr, N);
    gcn_gather<true, true, true><<<2048, 256, 0, stream>>>(hbf, offsets, esrc, dinv, b1, hbf2, N);

    // layer 3: GCN reordered (linearity): agg3 = A_norm h2 (gather bf16), out = agg3 @ W2 + b2
    gcn_gather<false, false, false><<<2048, 256, 0, stream>>>(hbf2, offsets, esrc, dinv, nullptr,
                                                              bufA, N);
    gemm_tiled<H_CH, false, false, true><<<NT, 512, 0, stream>>>(bufA, W2, out, nullptr, nullptr,
                                                                 nullptr, nullptr, b2, N);
}

// Round 11
// 207.295 us; speedup vs baseline: 1.2122x; 1.2122x over previous
//
#include <hip/hip_runtime.h>
#include <hip/hip_bf16.h>
#include <math.h>

#define IN_CH 128
#define H_CH  64
#define PBLK  256      // partition blocks (pass A/C grid)
#define PTHR  512      // threads for pass A/C
#define BKT   256      // nodes per bucket
#define MAXBK 400      // max buckets (N <= 102400)

typedef __attribute__((ext_vector_type(8))) short bf16x8;
typedef __attribute__((ext_vector_type(4))) float f32x4;

// ---------------- helpers ----------------

__device__ inline float bflo(unsigned u) { return __uint_as_float(u << 16); }
__device__ inline float bfhi(unsigned u) { return __uint_as_float(u & 0xffff0000u); }
__device__ inline unsigned short f2bf(float f) {   // round-to-nearest-even
    unsigned x = __float_as_uint(f);
    return (unsigned short)((x + 0x7fffu + ((x >> 16) & 1u)) >> 16);
}
__device__ inline bf16x8 pack8(float4 lo, float4 hi) {
    union { bf16x8 v; unsigned short u[8]; } r;
    r.u[0] = f2bf(lo.x); r.u[1] = f2bf(lo.y); r.u[2] = f2bf(lo.z); r.u[3] = f2bf(lo.w);
    r.u[4] = f2bf(hi.x); r.u[5] = f2bf(hi.y); r.u[6] = f2bf(hi.z); r.u[7] = f2bf(hi.w);
    return r.v;
}
__device__ inline float dot8(float4 a0, float4 a1, float4 b0, float4 b1) {
    return a0.x * b0.x + a0.y * b0.y + a0.z * b0.z + a0.w * b0.w
         + a1.x * b1.x + a1.y * b1.y + a1.z * b1.z + a1.w * b1.w;
}

// ---------------- CSR build: bucket partition, LDS atomics only ----------------

__global__ __launch_bounds__(PTHR) void passA(const int* __restrict__ ei, int E, int n,
                                              int nbk, int* __restrict__ blkhist) {
    __shared__ int hist[MAXBK];
    int tot = E + n;
    int CH = (tot + gridDim.x - 1) / gridDim.x;
    int beg = blockIdx.x * CH, end = min(tot, beg + CH);
    for (int k = threadIdx.x; k < nbk; k += blockDim.x) hist[k] = 0;
    __syncthreads();
    for (int idx = beg + threadIdx.x; idx < end; idx += blockDim.x) {
        int d = (idx < E) ? ei[E + idx] : (idx - E);
        atomicAdd(&hist[d >> 8], 1);
    }
    __syncthreads();
    for (int k = threadIdx.x; k < nbk; k += blockDim.x)
        blkhist[(size_t)blockIdx.x * nbk + k] = hist[k];
}

__global__ __launch_bounds__(PBLK) void passB1(const int* __restrict__ blkhist,
                                               int* __restrict__ blkbase,
                                               int* __restrict__ btot, int nbk) {
    __shared__ int sh[PBLK];
    int k = blockIdx.x, t = threadIdx.x;
    int v = blkhist[(size_t)t * nbk + k];
    sh[t] = v;
    __syncthreads();
    for (int off = 1; off < PBLK; off <<= 1) {
        int x = (t >= off) ? sh[t - off] : 0;
        __syncthreads();
        sh[t] += x;
        __syncthreads();
    }
    blkbase[(size_t)t * nbk + k] = sh[t] - v;
    if (t == PBLK - 1) btot[k] = sh[PBLK - 1];
}

__global__ __launch_bounds__(512) void passB2(const int* __restrict__ btot,
                                              int* __restrict__ bbase, int nbk, int tot) {
    __shared__ int sh[512];
    int t = threadIdx.x;
    int v = (t < nbk) ? btot[t] : 0;
    sh[t] = v;
    __syncthreads();
    for (int off = 1; off < 512; off <<= 1) {
        int x = (t >= off) ? sh[t - off] : 0;
        __syncthreads();
        sh[t] += x;
        __syncthreads();
    }
    if (t < nbk) bbase[t] = sh[t] - v;
    if (t == 0) bbase[nbk] = tot;
}

__global__ __launch_bounds__(PTHR) void passC(const int* __restrict__ ei, int E, int n, int nbk,
                                              const int* __restrict__ bbase,
                                              const int* __restrict__ blkbase,
                                              int2* __restrict__ pairs) {
    __shared__ int cur[MAXBK];
    int tot = E + n;
    int CH = (tot + gridDim.x - 1) / gridDim.x;
    int beg = blockIdx.x * CH, end = min(tot, beg + CH);
    for (int k = threadIdx.x; k < nbk; k += blockDim.x)
        cur[k] = bbase[k] + blkbase[(size_t)blockIdx.x * nbk + k];
    __syncthreads();
    for (int idx = beg + threadIdx.x; idx < end; idx += blockDim.x) {
        int s, d;
        if (idx < E) { s = ei[idx]; d = ei[E + idx]; }
        else         { s = idx - E; d = idx - E; }
        int pos = atomicAdd(&cur[d >> 8], 1);
        pairs[pos] = make_int2(s, d);
    }
}

__global__ __launch_bounds__(BKT) void passD(const int2* __restrict__ pairs,
                                             const int* __restrict__ bbase, int n, int nbk, int EP,
                                             int* __restrict__ esrc, int* __restrict__ offsets,
                                             float* __restrict__ dinv) {
    __shared__ int cnt[BKT];
    __shared__ int sh[BKT];
    __shared__ int cur[BKT];
    int k = blockIdx.x;
    int nbeg = k << 8;
    int t = threadIdx.x;
    int ebeg = bbase[k], eend = bbase[k + 1];
    cnt[t] = 0;
    __syncthreads();
    for (int e = ebeg + t; e < eend; e += BKT) {
        int2 p = pairs[e];
        atomicAdd(&cnt[p.y - nbeg], 1);
    }
    __syncthreads();
    int v = cnt[t];
    sh[t] = v;
    __syncthreads();
    for (int off = 1; off < BKT; off <<= 1) {
        int x = (t >= off) ? sh[t - off] : 0;
        __syncthreads();
        sh[t] += x;
        __syncthreads();
    }
    int lp = sh[t] - v;
    cur[t] = lp;
    int gn = nbeg + t;
    if (gn < n) {
        offsets[gn] = ebeg + lp;
        dinv[gn] = rsqrtf((float)v);
    }
    __syncthreads();
    for (int e = ebeg + t; e < eend; e += BKT) {
        int2 p = pairs[e];
        int pos = ebeg + atomicAdd(&cur[p.y - nbeg], 1);
        esrc[pos] = p.x;
    }
    if (k == 0 && t == 0) offsets[n] = EP;
}

// ---------------- alpha weight precompute: w_as = W @ att_src, w_ad = W @ att_dst ----------

__global__ void wprep(const float* __restrict__ W, const float* __restrict__ as,
                      const float* __restrict__ ad, float* __restrict__ w_as,
                      float* __restrict__ w_ad, int K) {
    int k = blockIdx.x * blockDim.x + threadIdx.x;
    if (k < K) {
        float s = 0.f, d = 0.f;
        for (int c = 0; c < H_CH; c++) {
            float w = W[(size_t)k * H_CH + c];
            s += w * as[c];
            d += w * ad[c];
        }
        w_as[k] = s;
        w_ad[k] = d;
    }
}

// ---------------- MFMA GEMM: wave = 16-row strip x 64 cols, 16x16x32 bf16 --------------
// r8/r9/r10: fp32-vector GEMM capped ~45us, K-independent -> structural wall; MFMA is
// the CDNA4 matmul path. Fragment layouts: A: row=lane&15, k=8*(lane>>4)+e;
// B: col=lane&15, k=8*(lane>>4)+e; C/D: col=lane&15, row=(lane>>4)*4+reg (m89-verified).
// W fragments register-resident (loaded once/wave, coalesced 64B per 16-lane group).
// GAT alphas from fp32 X dot precomputed (W@att) vectors -> alpha precision independent
// of bf16 (r4 FAILED with bf16-derived alphas). f2bf = RNE, matches prior rounds.

template <int K, bool GAT, bool OUTBF, bool BIASF>
__global__ __launch_bounds__(256) void mfma_gemm(const float* __restrict__ X,
                                                 const float* __restrict__ W,
                                                 void* __restrict__ outv,
                                                 const float* __restrict__ w_as,
                                                 const float* __restrict__ w_ad,
                                                 float* __restrict__ alpha_s,
                                                 float* __restrict__ alpha_d,
                                                 const float* __restrict__ bias, int n) {
    constexpr int KF = K / 32;
    int lane = threadIdx.x & 63;
    int wid  = threadIdx.x >> 6;
    int col  = lane & 15;     // B/D col within fragment; A row within strip
    int grp  = lane >> 4;

    // one-time: B fragments from W (K x 64 row-major fp32)
    bf16x8 bfr[KF][4];
#pragma unroll
    for (int kf = 0; kf < KF; kf++) {
        int kb = 32 * kf + 8 * grp;
#pragma unroll
        for (int cf = 0; cf < 4; cf++) {
            float w0[8];
#pragma unroll
            for (int e = 0; e < 8; e++)
                w0[e] = W[(size_t)(kb + e) * H_CH + 16 * cf + col];
            bfr[kf][cf] = pack8(make_float4(w0[0], w0[1], w0[2], w0[3]),
                                make_float4(w0[4], w0[5], w0[6], w0[7]));
        }
    }
    float bb[4] = {0.f, 0.f, 0.f, 0.f};
    if (BIASF) {
#pragma unroll
        for (int cf = 0; cf < 4; cf++) bb[cf] = bias[16 * cf + col];
    }

    int gw = blockIdx.x * (blockDim.x >> 6) + wid;
    int nw = gridDim.x * (blockDim.x >> 6);
    int ns = (n + 15) >> 4;
    for (int s = gw; s < ns; s += nw) {
        int r0 = s << 4;
        int r  = r0 + col;
        const float* xr = X + (size_t)(r < n ? r : 0) * K;
        bf16x8 afr[KF];
        float ps = 0.f, pd = 0.f;
#pragma unroll
        for (int kf = 0; kf < KF; kf++) {
            int kb = 32 * kf + 8 * grp;
            float4 x0 = *(const float4*)(xr + kb);
            float4 x1 = *(const float4*)(xr + kb + 4);
            if (GAT) {   // fp32 alpha partials from exact X (broadcast, L1-hot)
                float4 s0 = *(const float4*)(w_as + kb);
                float4 s1 = *(const float4*)(w_as + kb + 4);
                float4 d0 = *(const float4*)(w_ad + kb);
                float4 d1 = *(const float4*)(w_ad + kb + 4);
                ps += dot8(x0, x1, s0, s1);
                pd += dot8(x0, x1, d0, d1);
            }
            afr[kf] = pack8(x0, x1);
        }
        f32x4 acc[4];
#pragma unroll
        for (int cf = 0; cf < 4; cf++) {
            acc[cf] = (f32x4){0.f, 0.f, 0.f, 0.f};
#pragma unroll
            for (int kf = 0; kf < KF; kf++)
                acc[cf] = __builtin_amdgcn_mfma_f32_16x16x32_bf16(afr[kf], bfr[kf][cf],
                                                                  acc[cf], 0, 0, 0);
        }
#pragma unroll
        for (int cf = 0; cf < 4; cf++) {
            int cc = 16 * cf + col;
#pragma unroll
            for (int g = 0; g < 4; g++) {
                int rr = r0 + 4 * grp + g;
                if (rr < n) {
                    float v = acc[cf][g] + bb[cf];
                    if (OUTBF) ((unsigned short*)outv)[(size_t)rr * H_CH + cc] = f2bf(v);
                    else       ((float*)outv)[(size_t)rr * H_CH + cc] = v;
                }
            }
        }
        if (GAT) {
            ps += __shfl_xor(ps, 16, 64); ps += __shfl_xor(ps, 32, 64);
            pd += __shfl_xor(pd, 16, 64); pd += __shfl_xor(pd, 32, 64);
            if (grp == 0 && r < n) { alpha_s[r] = ps; alpha_d[r] = pd; }
        }
    }
}

// ---------------- GAT gather: quarter-wave edges, single-pass unnormalized softmax --------

__global__ __launch_bounds__(256) void gat_gather(const unsigned short* __restrict__ h,
                                                  const int* __restrict__ offs,
                                                  const int* __restrict__ esrc,
                                                  const float* __restrict__ as,
                                                  const float* __restrict__ ad,
                                                  const float* __restrict__ bias,
                                                  float* __restrict__ out, int n) {
    __shared__ int2 sh[4][64];
    int lane = threadIdx.x & 63;
    int wid  = threadIdx.x >> 6;
    int q = lane >> 4, c = lane & 15;
    int gw = (blockIdx.x * blockDim.x + threadIdx.x) >> 6;
    int nw = (gridDim.x * blockDim.x) >> 6;
    float4 bv = *(const float4*)(bias + 4 * c);
    for (int i = gw; i < n; i += nw) {
        int beg = offs[i], end = offs[i + 1];
        float adi = ad[i];
        float a0 = 0.f, a1 = 0.f, a2 = 0.f, a3 = 0.f, s = 0.f;
        for (int base = beg; base < end; base += 64) {
            int l = base + lane;
            int sj = 0; float p = 0.f;
            if (l < end) {
                sj = esrc[l];
                float a = as[sj] + adi;
                float ev = a > 0.f ? a : 0.2f * a;   // leaky_relu 0.2
                p = __expf(ev);
            }
            sh[wid][lane] = make_int2(sj, __float_as_int(p));
            int cnt = min(64, end - base);
            int k = 0;
            for (; k + 8 <= cnt; k += 8) {
                int2 tA = sh[wid][k + q];
                int2 tB = sh[wid][k + 4 + q];
                float pA = __int_as_float(tA.y);
                float pB = __int_as_float(tB.y);
                uint2 uA = *(const uint2*)(h + (size_t)tA.x * H_CH + 4 * c);
                uint2 uB = *(const uint2*)(h + (size_t)tB.x * H_CH + 4 * c);
                a0 += pA * bflo(uA.x); a1 += pA * bfhi(uA.x);
                a2 += pA * bflo(uA.y); a3 += pA * bfhi(uA.y);
                a0 += pB * bflo(uB.x); a1 += pB * bfhi(uB.x);
                a2 += pB * bflo(uB.y); a3 += pB * bfhi(uB.y);
                s += pA + pB;
            }
            for (; k < cnt; k += 4) {
                int2 tA = sh[wid][k + q];          // zero-padded entries safe
                float pA = __int_as_float(tA.y);
                uint2 uA = *(const uint2*)(h + (size_t)tA.x * H_CH + 4 * c);
                a0 += pA * bflo(uA.x); a1 += pA * bfhi(uA.x);
                a2 += pA * bflo(uA.y); a3 += pA * bfhi(uA.y);
                s += pA;
            }
        }
        a0 += __shfl_xor(a0, 16, 64); a0 += __shfl_xor(a0, 32, 64);
        a1 += __shfl_xor(a1, 16, 64); a1 += __shfl_xor(a1, 32, 64);
        a2 += __shfl_xor(a2, 16, 64); a2 += __shfl_xor(a2, 32, 64);
        a3 += __shfl_xor(a3, 16, 64); a3 += __shfl_xor(a3, 32, 64);
        s  += __shfl_xor(s, 16, 64);  s  += __shfl_xor(s, 32, 64);
        float invs = 1.f / (s + 1e-16f);
        if (q == 0) {
            float4 o;
            o.x = fmaxf(a0 * invs + bv.x, 0.f);   // relu
            o.y = fmaxf(a1 * invs + bv.y, 0.f);
            o.z = fmaxf(a2 * invs + bv.z, 0.f);
            o.w = fmaxf(a3 * invs + bv.w, 0.f);
            *(float4*)(out + (size_t)i * H_CH + 4 * c) = o;
        }
    }
}

// ---------------- GCN gather: quarter-wave edges, bf16 input ----------------

template <bool OUTBF, bool RELU, bool BIASF>
__global__ __launch_bounds__(256) void gcn_gather(const unsigned short* __restrict__ h,
                                                  const int* __restrict__ offs,
                                                  const int* __restrict__ esrc,
                                                  const float* __restrict__ dinv,
                                                  const float* __restrict__ bias,
                                                  void* __restrict__ outv, int n) {
    __shared__ int2 sh[4][64];
    int lane = threadIdx.x & 63;
    int wid  = threadIdx.x >> 6;
    int q = lane >> 4, c = lane & 15;
    int gw = (blockIdx.x * blockDim.x + threadIdx.x) >> 6;
    int nw = (gridDim.x * blockDim.x) >> 6;
    float4 bv = make_float4(0.f, 0.f, 0.f, 0.f);
    if (BIASF) bv = *(const float4*)(bias + 4 * c);
    for (int i = gw; i < n; i += nw) {
        int beg = offs[i], end = offs[i + 1];
        float a0 = 0.f, a1 = 0.f, a2 = 0.f, a3 = 0.f;
        for (int base = beg; base < end; base += 64) {
            int l = base + lane;
            int sj = 0; float wl = 0.f;
            if (l < end) { sj = esrc[l]; wl = dinv[sj]; }
            sh[wid][lane] = make_int2(sj, __float_as_int(wl));
            int cnt = min(64, end - base);
            int k = 0;
            for (; k + 8 <= cnt; k += 8) {
                int2 tA = sh[wid][k + q];
                int2 tB = sh[wid][k + 4 + q];
                float pA = __int_as_float(tA.y);
                float pB = __int_as_float(tB.y);
                uint2 uA = *(const uint2*)(h + (size_t)tA.x * H_CH + 4 * c);
                uint2 uB = *(const uint2*)(h + (size_t)tB.x * H_CH + 4 * c);
                a0 += pA * bflo(uA.x); a1 += pA * bfhi(uA.x);
                a2 += pA * bflo(uA.y); a3 += pA * bfhi(uA.y);
                a0 += pB * bflo(uB.x); a1 += pB * bfhi(uB.x);
                a2 += pB * bflo(uB.y); a3 += pB * bfhi(uB.y);
            }
            for (; k < cnt; k += 4) {
                int2 tA = sh[wid][k + q];
                float pA = __int_as_float(tA.y);
                uint2 uA = *(const uint2*)(h + (size_t)tA.x * H_CH + 4 * c);
                a0 += pA * bflo(uA.x); a1 += pA * bfhi(uA.x);
                a2 += pA * bflo(uA.y); a3 += pA * bfhi(uA.y);
            }
        }
        a0 += __shfl_xor(a0, 16, 64); a0 += __shfl_xor(a0, 32, 64);
        a1 += __shfl_xor(a1, 16, 64); a1 += __shfl_xor(a1, 32, 64);
        a2 += __shfl_xor(a2, 16, 64); a2 += __shfl_xor(a2, 32, 64);
        a3 += __shfl_xor(a3, 16, 64); a3 += __shfl_xor(a3, 32, 64);
        float di = dinv[i];
        if (q == 0) {
            float v0 = a0 * di + bv.x, v1 = a1 * di + bv.y;
            float v2 = a2 * di + bv.z, v3 = a3 * di + bv.w;
            if (RELU) {
                v0 = fmaxf(v0, 0.f); v1 = fmaxf(v1, 0.f);
                v2 = fmaxf(v2, 0.f); v3 = fmaxf(v3, 0.f);
            }
            if (OUTBF) {
                ushort4 o;
                o.x = f2bf(v0); o.y = f2bf(v1); o.z = f2bf(v2); o.w = f2bf(v3);
                *(ushort4*)((unsigned short*)outv + (size_t)i * H_CH + 4 * c) = o;
            } else {
                *(float4*)((float*)outv + (size_t)i * H_CH + 4 * c) =
                    make_float4(v0, v1, v2, v3);
            }
        }
    }
}

// ---------------- launch ----------------

extern "C" void kernel_launch(void* const* d_in, const int* in_sizes, int n_in,
                              void* d_out, int out_size, void* d_ws, size_t ws_size,
                              hipStream_t stream) {
    const float* x       = (const float*)d_in[0];
    const int*   ei      = (const int*)d_in[1];
    const float* W_gat   = (const float*)d_in[2];
    const float* att_src = (const float*)d_in[3];
    const float* att_dst = (const float*)d_in[4];
    const float* b_gat   = (const float*)d_in[5];
    const float* W1      = (const float*)d_in[6];
    const float* b1      = (const float*)d_in[7];
    const float* W2      = (const float*)d_in[8];
    const float* b2      = (const float*)d_in[9];
    float* out = (float*)d_out;

    const int N  = in_sizes[0] / IN_CH;
    const int E  = in_sizes[1] / 2;
    const int EP = E + N;
    const int NBK = (N + BKT - 1) / BKT;

    char* p = (char*)d_ws;
    auto alloc = [&](size_t bytes) -> void* {
        void* r = (void*)p;
        p += (bytes + 255) & ~(size_t)255;
        return r;
    };
    float* bufA    = (float*)alloc((size_t)N * H_CH * 4);   // fp32 scratch (gat out / agg3)
    unsigned short* hbf  = (unsigned short*)alloc((size_t)N * H_CH * 2);  // bf16 h
    unsigned short* hbf2 = (unsigned short*)alloc((size_t)N * H_CH * 2);  // bf16 h2
    float* alpha_s = (float*)alloc((size_t)N * 4);
    float* alpha_d = (float*)alloc((size_t)N * 4);
    float* dinv    = (float*)alloc((size_t)N * 4);
    float* w_as_g  = (float*)alloc((size_t)IN_CH * 4);
    float* w_ad_g  = (float*)alloc((size_t)IN_CH * 4);
    int*   offsets = (int*)alloc((size_t)(N + 1) * 4);
    int*   esrc    = (int*)alloc((size_t)EP * 4);
    int2*  pairs   = (int2*)alloc((size_t)EP * 8);
    int*   blkhist = (int*)alloc((size_t)PBLK * NBK * 4);
    int*   blkbase = (int*)alloc((size_t)PBLK * NBK * 4);
    int*   btot    = (int*)alloc((size_t)(NBK + 1) * 4);
    int*   bbase   = (int*)alloc((size_t)(NBK + 1) * 4);

    // alpha weight precompute (independent of CSR)
    wprep<<<1, 128, 0, stream>>>(W_gat, att_src, att_dst, w_as_g, w_ad_g, IN_CH);

    // CSR build (no global atomics, no memsets)
    passA<<<PBLK, PTHR, 0, stream>>>(ei, E, N, NBK, blkhist);
    passB1<<<NBK, PBLK, 0, stream>>>(blkhist, blkbase, btot, NBK);
    passB2<<<1, 512, 0, stream>>>(btot, bbase, NBK, EP);
    passC<<<PBLK, PTHR, 0, stream>>>(ei, E, N, NBK, bbase, blkbase, pairs);
    passD<<<NBK, BKT, 0, stream>>>(pairs, bbase, N, NBK, EP, esrc, offsets, dinv);

    // layer 1: GAT. MFMA gemm -> bf16 h; fp32 alphas from X dot (W@att); gather -> bufA
    mfma_gemm<IN_CH, true, true, false><<<512, 256, 0, stream>>>(x, W_gat, hbf, w_as_g, w_ad_g,
                                                                 alpha_s, alpha_d, nullptr, N);
    gat_gather<<<2048, 256, 0, stream>>>(hbf, offsets, esrc, alpha_s, alpha_d, b_gat, bufA, N);

    // layer 2: GCN + relu. MFMA gemm -> bf16 hbf; gather -> bf16 h2 (hbf2)
    mfma_gemm<H_CH, false, true, false><<<512, 256, 0, stream>>>(bufA, W1, hbf, nullptr, nullptr,
                                                                 nullptr, nullptr, nullptr, N);
    gcn_gather<true, true, true><<<2048, 256, 0, stream>>>(hbf, offsets, esrc, dinv, b1, hbf2, N);

    // layer 3: GCN reordered (linearity): agg3 = A_norm h2 (gather bf16), out = agg3 @ W2 + b2
    gcn_gather<false, false, false><<<2048, 256, 0, stream>>>(hbf2, offsets, esrc, dinv, nullptr,
                                                              bufA, N);
    mfma_gemm<H_CH, false, false, true><<<512, 256, 0, stream>>>(bufA, W2, out, nullptr, nullptr,
                                                                 nullptr, nullptr, b2, N);
}

// Round 12
// 205.614 us; speedup vs baseline: 1.2221x; 1.0082x over previous
//
#include <hip/hip_runtime.h>
#include <hip/hip_bf16.h>
#include <math.h>

#define IN_CH 128
#define H_CH  64
#define PBLK  256      // partition blocks (pass A/C grid)
#define PTHR  512      // threads for pass A/C
#define BKT   256      // nodes per bucket
#define MAXBK 400      // max buckets (N <= 102400)

typedef __attribute__((ext_vector_type(8))) short bf16x8;
typedef __attribute__((ext_vector_type(4))) float f32x4;

// ---------------- helpers ----------------

__device__ inline float bflo(unsigned u) { return __uint_as_float(u << 16); }
__device__ inline float bfhi(unsigned u) { return __uint_as_float(u & 0xffff0000u); }
__device__ inline unsigned short f2bf(float f) {   // round-to-nearest-even
    unsigned x = __float_as_uint(f);
    return (unsigned short)((x + 0x7fffu + ((x >> 16) & 1u)) >> 16);
}
__device__ inline bf16x8 pack8(float4 lo, float4 hi) {
    union { bf16x8 v; unsigned short u[8]; } r;
    r.u[0] = f2bf(lo.x); r.u[1] = f2bf(lo.y); r.u[2] = f2bf(lo.z); r.u[3] = f2bf(lo.w);
    r.u[4] = f2bf(hi.x); r.u[5] = f2bf(hi.y); r.u[6] = f2bf(hi.z); r.u[7] = f2bf(hi.w);
    return r.v;
}
__device__ inline float dot8(float4 a0, float4 a1, float4 b0, float4 b1) {
    return a0.x * b0.x + a0.y * b0.y + a0.z * b0.z + a0.w * b0.w
         + a1.x * b1.x + a1.y * b1.y + a1.z * b1.z + a1.w * b1.w;
}

// ---------------- CSR build: bucket partition, LDS atomics only ----------------

__global__ __launch_bounds__(PTHR) void passA(const int* __restrict__ ei, int E, int n,
                                              int nbk, int* __restrict__ blkhist) {
    __shared__ int hist[MAXBK];
    int tot = E + n;
    int CH = (tot + gridDim.x - 1) / gridDim.x;
    int beg = blockIdx.x * CH, end = min(tot, beg + CH);
    for (int k = threadIdx.x; k < nbk; k += blockDim.x) hist[k] = 0;
    __syncthreads();
    for (int idx = beg + threadIdx.x; idx < end; idx += blockDim.x) {
        int d = (idx < E) ? ei[E + idx] : (idx - E);
        atomicAdd(&hist[d >> 8], 1);
    }
    __syncthreads();
    for (int k = threadIdx.x; k < nbk; k += blockDim.x)
        blkhist[(size_t)blockIdx.x * nbk + k] = hist[k];
}

__global__ __launch_bounds__(PBLK) void passB1(const int* __restrict__ blkhist,
                                               int* __restrict__ blkbase,
                                               int* __restrict__ btot, int nbk) {
    __shared__ int sh[PBLK];
    int k = blockIdx.x, t = threadIdx.x;
    int v = blkhist[(size_t)t * nbk + k];
    sh[t] = v;
    __syncthreads();
    for (int off = 1; off < PBLK; off <<= 1) {
        int x = (t >= off) ? sh[t - off] : 0;
        __syncthreads();
        sh[t] += x;
        __syncthreads();
    }
    blkbase[(size_t)t * nbk + k] = sh[t] - v;
    if (t == PBLK - 1) btot[k] = sh[PBLK - 1];
}

__global__ __launch_bounds__(512) void passB2(const int* __restrict__ btot,
                                              int* __restrict__ bbase, int nbk, int tot) {
    __shared__ int sh[512];
    int t = threadIdx.x;
    int v = (t < nbk) ? btot[t] : 0;
    sh[t] = v;
    __syncthreads();
    for (int off = 1; off < 512; off <<= 1) {
        int x = (t >= off) ? sh[t - off] : 0;
        __syncthreads();
        sh[t] += x;
        __syncthreads();
    }
    if (t < nbk) bbase[t] = sh[t] - v;
    if (t == 0) bbase[nbk] = tot;
}

__global__ __launch_bounds__(PTHR) void passC(const int* __restrict__ ei, int E, int n, int nbk,
                                              const int* __restrict__ bbase,
                                              const int* __restrict__ blkbase,
                                              int2* __restrict__ pairs) {
    __shared__ int cur[MAXBK];
    int tot = E + n;
    int CH = (tot + gridDim.x - 1) / gridDim.x;
    int beg = blockIdx.x * CH, end = min(tot, beg + CH);
    for (int k = threadIdx.x; k < nbk; k += blockDim.x)
        cur[k] = bbase[k] + blkbase[(size_t)blockIdx.x * nbk + k];
    __syncthreads();
    for (int idx = beg + threadIdx.x; idx < end; idx += blockDim.x) {
        int s, d;
        if (idx < E) { s = ei[idx]; d = ei[E + idx]; }
        else         { s = idx - E; d = idx - E; }
        int pos = atomicAdd(&cur[d >> 8], 1);
        pairs[pos] = make_int2(s, d);
    }
}

__global__ __launch_bounds__(BKT) void passD(const int2* __restrict__ pairs,
                                             const int* __restrict__ bbase, int n, int nbk, int EP,
                                             int* __restrict__ esrc, int* __restrict__ offsets,
                                             float* __restrict__ dinv) {
    __shared__ int cnt[BKT];
    __shared__ int sh[BKT];
    __shared__ int cur[BKT];
    int k = blockIdx.x;
    int nbeg = k << 8;
    int t = threadIdx.x;
    int ebeg = bbase[k], eend = bbase[k + 1];
    cnt[t] = 0;
    __syncthreads();
    for (int e = ebeg + t; e < eend; e += BKT) {
        int2 p = pairs[e];
        atomicAdd(&cnt[p.y - nbeg], 1);
    }
    __syncthreads();
    int v = cnt[t];
    sh[t] = v;
    __syncthreads();
    for (int off = 1; off < BKT; off <<= 1) {
        int x = (t >= off) ? sh[t - off] : 0;
        __syncthreads();
        sh[t] += x;
        __syncthreads();
    }
    int lp = sh[t] - v;
    cur[t] = lp;
    int gn = nbeg + t;
    if (gn < n) {
        offsets[gn] = ebeg + lp;
        dinv[gn] = rsqrtf((float)v);
    }
    __syncthreads();
    for (int e = ebeg + t; e < eend; e += BKT) {
        int2 p = pairs[e];
        int pos = ebeg + atomicAdd(&cur[p.y - nbeg], 1);
        esrc[pos] = p.x;
    }
    if (k == 0 && t == 0) offsets[n] = EP;
}

// ---------------- alpha weight precompute: w_as = W @ att_src, w_ad = W @ att_dst ----------

__global__ void wprep(const float* __restrict__ W, const float* __restrict__ as,
                      const float* __restrict__ ad, float* __restrict__ w_as,
                      float* __restrict__ w_ad, int K) {
    int k = blockIdx.x * blockDim.x + threadIdx.x;
    if (k < K) {
        float s = 0.f, d = 0.f;
        for (int c = 0; c < H_CH; c++) {
            float w = W[(size_t)k * H_CH + c];
            s += w * as[c];
            d += w * ad[c];
        }
        w_as[k] = s;
        w_ad[k] = d;
    }
}

// ---------------- MFMA GEMM: wave = 16-row strip x 64 cols, 16x16x32 bf16 --------------
// TIN=float: fp32 rows packed to bf16 in-register (RNE). TIN=ushort: rows already
// bf16 -> direct 16B fragment loads (bitwise-identical result, since upstream
// writer used the same f2bf). GAT alphas from fp32 X dot (W@att) -> exact (r4 lesson).
// Layouts m89-verified: A row=lane&15,k=8*(lane>>4)+e; C/D col=lane&15,row=4*(lane>>4)+reg.

template <int K, bool GAT, bool OUTBF, bool BIASF, typename TIN>
__global__ __launch_bounds__(256) void mfma_gemm(const TIN* __restrict__ X,
                                                 const float* __restrict__ W,
                                                 void* __restrict__ outv,
                                                 const float* __restrict__ w_as,
                                                 const float* __restrict__ w_ad,
                                                 float* __restrict__ alpha_s,
                                                 float* __restrict__ alpha_d,
                                                 const float* __restrict__ bias, int n) {
    constexpr int KF = K / 32;
    int lane = threadIdx.x & 63;
    int wid  = threadIdx.x >> 6;
    int col  = lane & 15;
    int grp  = lane >> 4;

    bf16x8 bfr[KF][4];
#pragma unroll
    for (int kf = 0; kf < KF; kf++) {
        int kb = 32 * kf + 8 * grp;
#pragma unroll
        for (int cf = 0; cf < 4; cf++) {
            float w0[8];
#pragma unroll
            for (int e = 0; e < 8; e++)
                w0[e] = W[(size_t)(kb + e) * H_CH + 16 * cf + col];
            bfr[kf][cf] = pack8(make_float4(w0[0], w0[1], w0[2], w0[3]),
                                make_float4(w0[4], w0[5], w0[6], w0[7]));
        }
    }
    float bb[4] = {0.f, 0.f, 0.f, 0.f};
    if (BIASF) {
#pragma unroll
        for (int cf = 0; cf < 4; cf++) bb[cf] = bias[16 * cf + col];
    }

    int gw = blockIdx.x * (blockDim.x >> 6) + wid;
    int nw = gridDim.x * (blockDim.x >> 6);
    int ns = (n + 15) >> 4;
    for (int s = gw; s < ns; s += nw) {
        int r0 = s << 4;
        int r  = r0 + col;
        const TIN* xr = X + (size_t)(r < n ? r : 0) * K;
        bf16x8 afr[KF];
        float ps = 0.f, pd = 0.f;
#pragma unroll
        for (int kf = 0; kf < KF; kf++) {
            int kb = 32 * kf + 8 * grp;
            if constexpr (sizeof(TIN) == 2) {
                afr[kf] = *(const bf16x8*)(xr + kb);
            } else {
                float4 x0 = *(const float4*)(xr + kb);
                float4 x1 = *(const float4*)(xr + kb + 4);
                if (GAT) {
                    float4 s0 = *(const float4*)(w_as + kb);
                    float4 s1 = *(const float4*)(w_as + kb + 4);
                    float4 d0 = *(const float4*)(w_ad + kb);
                    float4 d1 = *(const float4*)(w_ad + kb + 4);
                    ps += dot8(x0, x1, s0, s1);
                    pd += dot8(x0, x1, d0, d1);
                }
                afr[kf] = pack8(x0, x1);
            }
        }
        f32x4 acc[4];
#pragma unroll
        for (int cf = 0; cf < 4; cf++) {
            acc[cf] = (f32x4){0.f, 0.f, 0.f, 0.f};
#pragma unroll
            for (int kf = 0; kf < KF; kf++)
                acc[cf] = __builtin_amdgcn_mfma_f32_16x16x32_bf16(afr[kf], bfr[kf][cf],
                                                                  acc[cf], 0, 0, 0);
        }
#pragma unroll
        for (int cf = 0; cf < 4; cf++) {
            int cc = 16 * cf + col;
#pragma unroll
            for (int g = 0; g < 4; g++) {
                int rr = r0 + 4 * grp + g;
                if (rr < n) {
                    float v = acc[cf][g] + bb[cf];
                    if (OUTBF) ((unsigned short*)outv)[(size_t)rr * H_CH + cc] = f2bf(v);
                    else       ((float*)outv)[(size_t)rr * H_CH + cc] = v;
                }
            }
        }
        if (GAT) {
            ps += __shfl_xor(ps, 16, 64); ps += __shfl_xor(ps, 32, 64);
            pd += __shfl_xor(pd, 16, 64); pd += __shfl_xor(pd, 32, 64);
            if (grp == 0 && r < n) { alpha_s[r] = ps; alpha_d[r] = pd; }
        }
    }
}

// ---------------- GAT gather: quarter-wave edges, 16 edges/iter, bf16 out ----------------
// Single-pass unnormalized softmax (|e| bounded for this data -> exact).
// 4 row-loads in flight per lane (r11: 2-deep, gathers latency-bound at ~5 TB/s logical).

__global__ __launch_bounds__(256) void gat_gather(const unsigned short* __restrict__ h,
                                                  const int* __restrict__ offs,
                                                  const int* __restrict__ esrc,
                                                  const float* __restrict__ as,
                                                  const float* __restrict__ ad,
                                                  const float* __restrict__ bias,
                                                  unsigned short* __restrict__ out, int n) {
    __shared__ int2 sh[4][64];
    int lane = threadIdx.x & 63;
    int wid  = threadIdx.x >> 6;
    int q = lane >> 4, c = lane & 15;
    int gw = (blockIdx.x * blockDim.x + threadIdx.x) >> 6;
    int nw = (gridDim.x * blockDim.x) >> 6;
    float4 bv = *(const float4*)(bias + 4 * c);
    for (int i = gw; i < n; i += nw) {
        int beg = offs[i], end = offs[i + 1];
        float adi = ad[i];
        float a0 = 0.f, a1 = 0.f, a2 = 0.f, a3 = 0.f, s = 0.f;
        for (int base = beg; base < end; base += 64) {
            int l = base + lane;
            int sj = 0; float p = 0.f;
            if (l < end) {
                sj = esrc[l];
                float a = as[sj] + adi;
                float ev = a > 0.f ? a : 0.2f * a;   // leaky_relu 0.2
                p = __expf(ev);
            }
            sh[wid][lane] = make_int2(sj, __float_as_int(p));
            int cnt = min(64, end - base);
            int k = 0;
            for (; k + 16 <= cnt; k += 16) {
                int2 t0 = sh[wid][k + q];
                int2 t1 = sh[wid][k + 4 + q];
                int2 t2 = sh[wid][k + 8 + q];
                int2 t3 = sh[wid][k + 12 + q];
                float p0 = __int_as_float(t0.y), p1 = __int_as_float(t1.y);
                float p2 = __int_as_float(t2.y), p3 = __int_as_float(t3.y);
                uint2 u0 = *(const uint2*)(h + (size_t)t0.x * H_CH + 4 * c);
                uint2 u1 = *(const uint2*)(h + (size_t)t1.x * H_CH + 4 * c);
                uint2 u2 = *(const uint2*)(h + (size_t)t2.x * H_CH + 4 * c);
                uint2 u3 = *(const uint2*)(h + (size_t)t3.x * H_CH + 4 * c);
                a0 += p0 * bflo(u0.x); a1 += p0 * bfhi(u0.x);
                a2 += p0 * bflo(u0.y); a3 += p0 * bfhi(u0.y);
                a0 += p1 * bflo(u1.x); a1 += p1 * bfhi(u1.x);
                a2 += p1 * bflo(u1.y); a3 += p1 * bfhi(u1.y);
                a0 += p2 * bflo(u2.x); a1 += p2 * bfhi(u2.x);
                a2 += p2 * bflo(u2.y); a3 += p2 * bfhi(u2.y);
                a0 += p3 * bflo(u3.x); a1 += p3 * bfhi(u3.x);
                a2 += p3 * bflo(u3.y); a3 += p3 * bfhi(u3.y);
                s += p0 + p1 + p2 + p3;
            }
            for (; k < cnt; k += 4) {
                int2 t0 = sh[wid][k + q];          // zero-padded entries safe
                float p0 = __int_as_float(t0.y);
                uint2 u0 = *(const uint2*)(h + (size_t)t0.x * H_CH + 4 * c);
                a0 += p0 * bflo(u0.x); a1 += p0 * bfhi(u0.x);
                a2 += p0 * bflo(u0.y); a3 += p0 * bfhi(u0.y);
                s += p0;
            }
        }
        a0 += __shfl_xor(a0, 16, 64); a0 += __shfl_xor(a0, 32, 64);
        a1 += __shfl_xor(a1, 16, 64); a1 += __shfl_xor(a1, 32, 64);
        a2 += __shfl_xor(a2, 16, 64); a2 += __shfl_xor(a2, 32, 64);
        a3 += __shfl_xor(a3, 16, 64); a3 += __shfl_xor(a3, 32, 64);
        s  += __shfl_xor(s, 16, 64);  s  += __shfl_xor(s, 32, 64);
        float invs = 1.f / (s + 1e-16f);
        if (q == 0) {
            ushort4 o;
            o.x = f2bf(fmaxf(a0 * invs + bv.x, 0.f));   // relu
            o.y = f2bf(fmaxf(a1 * invs + bv.y, 0.f));
            o.z = f2bf(fmaxf(a2 * invs + bv.z, 0.f));
            o.w = f2bf(fmaxf(a3 * invs + bv.w, 0.f));
            *(ushort4*)(out + (size_t)i * H_CH + 4 * c) = o;
        }
    }
}

// ---------------- GCN gather: quarter-wave edges, 16 edges/iter, bf16 in/out --------------
// OUTBF always now (both consumers take bf16; bf16 write is the SAME f2bf the GEMM
// would apply -> bitwise-identical, halves write+read traffic).

template <bool RELU, bool BIASF>
__global__ __launch_bounds__(256) void gcn_gather(const unsigned short* __restrict__ h,
                                                  const int* __restrict__ offs,
                                                  const int* __restrict__ esrc,
                                                  const float* __restrict__ dinv,
                                                  const float* __restrict__ bias,
                                                  unsigned short* __restrict__ out, int n) {
    __shared__ int2 sh[4][64];
    int lane = threadIdx.x & 63;
    int wid  = threadIdx.x >> 6;
    int q = lane >> 4, c = lane & 15;
    int gw = (blockIdx.x * blockDim.x + threadIdx.x) >> 6;
    int nw = (gridDim.x * blockDim.x) >> 6;
    float4 bv = make_float4(0.f, 0.f, 0.f, 0.f);
    if (BIASF) bv = *(const float4*)(bias + 4 * c);
    for (int i = gw; i < n; i += nw) {
        int beg = offs[i], end = offs[i + 1];
        float a0 = 0.f, a1 = 0.f, a2 = 0.f, a3 = 0.f;
        for (int base = beg; base < end; base += 64) {
            int l = base + lane;
            int sj = 0; float wl = 0.f;
            if (l < end) { sj = esrc[l]; wl = dinv[sj]; }
            sh[wid][lane] = make_int2(sj, __float_as_int(wl));
            int cnt = min(64, end - base);
            int k = 0;
            for (; k + 16 <= cnt; k += 16) {
                int2 t0 = sh[wid][k + q];
                int2 t1 = sh[wid][k + 4 + q];
                int2 t2 = sh[wid][k + 8 + q];
                int2 t3 = sh[wid][k + 12 + q];
                float p0 = __int_as_float(t0.y), p1 = __int_as_float(t1.y);
                float p2 = __int_as_float(t2.y), p3 = __int_as_float(t3.y);
                uint2 u0 = *(const uint2*)(h + (size_t)t0.x * H_CH + 4 * c);
                uint2 u1 = *(const uint2*)(h + (size_t)t1.x * H_CH + 4 * c);
                uint2 u2 = *(const uint2*)(h + (size_t)t2.x * H_CH + 4 * c);
                uint2 u3 = *(const uint2*)(h + (size_t)t3.x * H_CH + 4 * c);
                a0 += p0 * bflo(u0.x); a1 += p0 * bfhi(u0.x);
                a2 += p0 * bflo(u0.y); a3 += p0 * bfhi(u0.y);
                a0 += p1 * bflo(u1.x); a1 += p1 * bfhi(u1.x);
                a2 += p1 * bflo(u1.y); a3 += p1 * bfhi(u1.y);
                a0 += p2 * bflo(u2.x); a1 += p2 * bfhi(u2.x);
                a2 += p2 * bflo(u2.y); a3 += p2 * bfhi(u2.y);
                a0 += p3 * bflo(u3.x); a1 += p3 * bfhi(u3.x);
                a2 += p3 * bflo(u3.y); a3 += p3 * bfhi(u3.y);
            }
            for (; k < cnt; k += 4) {
                int2 t0 = sh[wid][k + q];
                float p0 = __int_as_float(t0.y);
                uint2 u0 = *(const uint2*)(h + (size_t)t0.x * H_CH + 4 * c);
                a0 += p0 * bflo(u0.x); a1 += p0 * bfhi(u0.x);
                a2 += p0 * bflo(u0.y); a3 += p0 * bfhi(u0.y);
            }
        }
        a0 += __shfl_xor(a0, 16, 64); a0 += __shfl_xor(a0, 32, 64);
        a1 += __shfl_xor(a1, 16, 64); a1 += __shfl_xor(a1, 32, 64);
        a2 += __shfl_xor(a2, 16, 64); a2 += __shfl_xor(a2, 32, 64);
        a3 += __shfl_xor(a3, 16, 64); a3 += __shfl_xor(a3, 32, 64);
        float di = dinv[i];
        if (q == 0) {
            float v0 = a0 * di + bv.x, v1 = a1 * di + bv.y;
            float v2 = a2 * di + bv.z, v3 = a3 * di + bv.w;
            if (RELU) {
                v0 = fmaxf(v0, 0.f); v1 = fmaxf(v1, 0.f);
                v2 = fmaxf(v2, 0.f); v3 = fmaxf(v3, 0.f);
            }
            ushort4 o;
            o.x = f2bf(v0); o.y = f2bf(v1); o.z = f2bf(v2); o.w = f2bf(v3);
            *(ushort4*)(out + (size_t)i * H_CH + 4 * c) = o;
        }
    }
}

// ---------------- launch ----------------

extern "C" void kernel_launch(void* const* d_in, const int* in_sizes, int n_in,
                              void* d_out, int out_size, void* d_ws, size_t ws_size,
                              hipStream_t stream) {
    const float* x       = (const float*)d_in[0];
    const int*   ei      = (const int*)d_in[1];
    const float* W_gat   = (const float*)d_in[2];
    const float* att_src = (const float*)d_in[3];
    const float* att_dst = (const float*)d_in[4];
    const float* b_gat   = (const float*)d_in[5];
    const float* W1      = (const float*)d_in[6];
    const float* b1      = (const float*)d_in[7];
    const float* W2      = (const float*)d_in[8];
    const float* b2      = (const float*)d_in[9];
    float* out = (float*)d_out;

    const int N  = in_sizes[0] / IN_CH;
    const int E  = in_sizes[1] / 2;
    const int EP = E + N;
    const int NBK = (N + BKT - 1) / BKT;

    char* p = (char*)d_ws;
    auto alloc = [&](size_t bytes) -> void* {
        void* r = (void*)p;
        p += (bytes + 255) & ~(size_t)255;
        return r;
    };
    unsigned short* hbf  = (unsigned short*)alloc((size_t)N * H_CH * 2);  // gemm1/2 out
    unsigned short* hbfA = (unsigned short*)alloc((size_t)N * H_CH * 2);  // gat out / agg3
    unsigned short* hbf2 = (unsigned short*)alloc((size_t)N * H_CH * 2);  // layer2 gather out
    float* alpha_s = (float*)alloc((size_t)N * 4);
    float* alpha_d = (float*)alloc((size_t)N * 4);
    float* dinv    = (float*)alloc((size_t)N * 4);
    float* w_as_g  = (float*)alloc((size_t)IN_CH * 4);
    float* w_ad_g  = (float*)alloc((size_t)IN_CH * 4);
    int*   offsets = (int*)alloc((size_t)(N + 1) * 4);
    int*   esrc    = (int*)alloc((size_t)EP * 4);
    int2*  pairs   = (int2*)alloc((size_t)EP * 8);
    int*   blkhist = (int*)alloc((size_t)PBLK * NBK * 4);
    int*   blkbase = (int*)alloc((size_t)PBLK * NBK * 4);
    int*   btot    = (int*)alloc((size_t)(NBK + 1) * 4);
    int*   bbase   = (int*)alloc((size_t)(NBK + 1) * 4);

    // alpha weight precompute (independent of CSR)
    wprep<<<1, 128, 0, stream>>>(W_gat, att_src, att_dst, w_as_g, w_ad_g, IN_CH);

    // CSR build (no global atomics, no memsets)
    passA<<<PBLK, PTHR, 0, stream>>>(ei, E, N, NBK, blkhist);
    passB1<<<NBK, PBLK, 0, stream>>>(blkhist, blkbase, btot, NBK);
    passB2<<<1, 512, 0, stream>>>(btot, bbase, NBK, EP);
    passC<<<PBLK, PTHR, 0, stream>>>(ei, E, N, NBK, bbase, blkbase, pairs);
    passD<<<NBK, BKT, 0, stream>>>(pairs, bbase, N, NBK, EP, esrc, offsets, dinv);

    // layer 1: GAT. MFMA gemm (fp32 in) -> bf16 h; fp32 alphas; gather -> bf16 hbfA
    mfma_gemm<IN_CH, true, true, false, float><<<512, 256, 0, stream>>>(
        x, W_gat, hbf, w_as_g, w_ad_g, alpha_s, alpha_d, nullptr, N);
    gat_gather<<<2048, 256, 0, stream>>>(hbf, offsets, esrc, alpha_s, alpha_d, b_gat, hbfA, N);

    // layer 2: GCN + relu. MFMA gemm (bf16 in) -> bf16 hbf; gather -> bf16 hbf2
    mfma_gemm<H_CH, false, true, false, unsigned short><<<512, 256, 0, stream>>>(
        hbfA, W1, hbf, nullptr, nullptr, nullptr, nullptr, nullptr, N);
    gcn_gather<true, true><<<2048, 256, 0, stream>>>(hbf, offsets, esrc, dinv, b1, hbf2, N);

    // layer 3: GCN reordered (linearity): agg3 = A_norm h2 (bf16), out = agg3 @ W2 + b2
    gcn_gather<false, false><<<2048, 256, 0, stream>>>(hbf2, offsets, esrc, dinv, nullptr,
                                                       hbfA, N);
    mfma_gemm<H_CH, false, false, true, unsigned short><<<512, 256, 0, stream>>>(
        hbfA, W2, out, nullptr, nullptr, nullptr, nullptr, b2, N);
}